// Round 1
// baseline (1125.858 us; speedup 1.0000x reference)
//
#include <hip/hip_runtime.h>
#include <math.h>

#define D_MODEL 768
#define D_INNER 1536
#define D_STATE 16
#define DT_RANK 96
#define H_FFN 2048
#define LSEQ 2048
#define XDBL_W (DT_RANK + 2*D_STATE)   // 128
#define NCHUNK 32
#define LCHUNK 64

// ---------------- RMSNorm: one block per row (768 = 256*3) ----------------
__global__ __launch_bounds__(256) void rmsnorm_kernel(const float* __restrict__ x,
        const float* __restrict__ w, float* __restrict__ out) {
    int row = blockIdx.x;
    const float* xr = x + (long)row * D_MODEL;
    float v0 = xr[threadIdx.x];
    float v1 = xr[threadIdx.x + 256];
    float v2 = xr[threadIdx.x + 512];
    float ss = v0*v0 + v1*v1 + v2*v2;
    #pragma unroll
    for (int off = 32; off > 0; off >>= 1) ss += __shfl_down(ss, off, 64);
    __shared__ float red[4];
    __shared__ float scale_sh;
    int wave = threadIdx.x >> 6;
    int lane = threadIdx.x & 63;
    if (lane == 0) red[wave] = ss;
    __syncthreads();
    if (threadIdx.x == 0) {
        float tot = red[0] + red[1] + red[2] + red[3];
        scale_sh = rsqrtf(tot / (float)D_MODEL + 1e-6f);
    }
    __syncthreads();
    float sc = scale_sh;
    float* orow = out + (long)row * D_MODEL;
    orow[threadIdx.x]       = v0 * sc * w[threadIdx.x];
    orow[threadIdx.x + 256] = v1 * sc * w[threadIdx.x + 256];
    orow[threadIdx.x + 512] = v2 * sc * w[threadIdx.x + 512];
}

// ---------------- fp32 GEMM: C[M,N] = A[M,K](lda) @ B[N,K](ldb)^T (+Res) ----
// 64x64 block tile, 256 threads, 4x4 per-thread microtile, K-step 16.
template<int EPI>
__global__ __launch_bounds__(256) void gemm_tn(const float* __restrict__ A, int lda,
        const float* __restrict__ B, int ldb,
        const float* __restrict__ Res, float* __restrict__ C,
        int N, int K) {
    __shared__ float As[16][65];
    __shared__ float Bs[16][65];
    int tid = threadIdx.x;
    int tx = tid & 15, ty = tid >> 4;
    int m0 = blockIdx.y << 6, n0 = blockIdx.x << 6;
    int lr = tid >> 2, lc = (tid & 3) << 2;
    const float* Aload = A + (long)(m0 + lr) * lda + lc;
    const float* Bload = B + (long)(n0 + lr) * ldb + lc;
    float acc[4][4] = {};
    for (int k0 = 0; k0 < K; k0 += 16) {
        float4 av = *(const float4*)(Aload + k0);
        float4 bv = *(const float4*)(Bload + k0);
        As[lc+0][lr] = av.x; As[lc+1][lr] = av.y; As[lc+2][lr] = av.z; As[lc+3][lr] = av.w;
        Bs[lc+0][lr] = bv.x; Bs[lc+1][lr] = bv.y; Bs[lc+2][lr] = bv.z; Bs[lc+3][lr] = bv.w;
        __syncthreads();
        #pragma unroll
        for (int kk = 0; kk < 16; ++kk) {
            float a[4], b[4];
            #pragma unroll
            for (int i = 0; i < 4; i++) a[i] = As[kk][ty + (i<<4)];
            #pragma unroll
            for (int j = 0; j < 4; j++) b[j] = Bs[kk][tx + (j<<4)];
            #pragma unroll
            for (int i = 0; i < 4; i++)
                #pragma unroll
                for (int j = 0; j < 4; j++) acc[i][j] = fmaf(a[i], b[j], acc[i][j]);
        }
        __syncthreads();
    }
    #pragma unroll
    for (int i = 0; i < 4; i++) {
        int m = m0 + ty + (i<<4);
        #pragma unroll
        for (int j = 0; j < 4; j++) {
            int n = n0 + tx + (j<<4);
            long idx = (long)m * N + n;
            float v = acc[i][j];
            if (EPI == 1) v += Res[idx];
            C[idx] = v;
        }
    }
}

// ---------------- elementwise ----------------
__global__ void ew_gate(const float* a, const float* g, float* o, int n) {
    int i = blockIdx.x * blockDim.x + threadIdx.x;
    int stride = gridDim.x * blockDim.x;
    for (; i < n; i += stride) {
        float gv = g[i];
        o[i] = a[i] / (1.f + expf(-gv));
    }
}

__global__ void ew_silu_mul(float* up, const float* gf, int n) {
    int i = blockIdx.x * blockDim.x + threadIdx.x;
    int stride = gridDim.x * blockDim.x;
    for (; i < n; i += stride) {
        float g = gf[i];
        up[i] = up[i] * g / (1.f + expf(-g));
    }
}

// ---------------- selective scan (3-pass chunked) ----------------
__device__ __forceinline__ float softplus_f(float x) {
    return (x > 20.f) ? x : log1pf(expf(x));
}

__global__ __launch_bounds__(256) void scan_pass1(const float* __restrict__ dt0,
        const float* __restrict__ b_dt, const float* __restrict__ z,
        const float* __restrict__ xdbl, const float* __restrict__ A_log,
        float* __restrict__ Aprod, float* __restrict__ hend) {
    int c = blockIdx.x;
    int d = blockIdx.y * 256 + threadIdx.x;
    float negA[16], Ap[16], hh[16];
    #pragma unroll
    for (int s = 0; s < 16; s++) {
        negA[s] = -expf(A_log[d*16 + s]);
        Ap[s] = 1.f; hh[s] = 0.f;
    }
    float bd = b_dt[d];
    int t0 = c * LCHUNK;
    for (int t = t0; t < t0 + LCHUNK; ++t) {
        float dtv = softplus_f(dt0[(long)t*D_INNER + d] + bd);
        float zv = z[(long)t*D_INNER + d];
        float dz = dtv * zv;
        const float* xb = xdbl + (long)t*XDBL_W + DT_RANK;
        #pragma unroll
        for (int s = 0; s < 16; s++) {
            float ab = expf(dtv * negA[s]);
            hh[s] = fmaf(ab, hh[s], dz * xb[s]);
            Ap[s] *= ab;
        }
    }
    long base = ((long)c * D_INNER + d) * 16;
    #pragma unroll
    for (int s = 0; s < 16; s++) { Aprod[base+s] = Ap[s]; hend[base+s] = hh[s]; }
}

__global__ __launch_bounds__(256) void scan_pass2(const float* __restrict__ Aprod,
        const float* __restrict__ hend, float* __restrict__ carryin) {
    int d = blockIdx.x * 256 + threadIdx.x;
    float carry[16];
    #pragma unroll
    for (int s = 0; s < 16; s++) carry[s] = 0.f;
    for (int c = 0; c < NCHUNK; c++) {
        long base = ((long)c * D_INNER + d) * 16;
        #pragma unroll
        for (int s = 0; s < 16; s++) {
            carryin[base+s] = carry[s];
            carry[s] = fmaf(Aprod[base+s], carry[s], hend[base+s]);
        }
    }
}

// y written in-place over z (per-element read-then-write by same thread; no __restrict__)
__global__ __launch_bounds__(256) void scan_pass3(const float* __restrict__ dt0,
        const float* __restrict__ b_dt, const float* zin,
        const float* __restrict__ xdbl, const float* __restrict__ A_log,
        const float* __restrict__ carryin, const float* __restrict__ D_skip,
        float* y) {
    int c = blockIdx.x;
    int d = blockIdx.y * 256 + threadIdx.x;
    float negA[16], hh[16];
    long cb = ((long)c * D_INNER + d) * 16;
    #pragma unroll
    for (int s = 0; s < 16; s++) {
        negA[s] = -expf(A_log[d*16 + s]);
        hh[s] = carryin[cb + s];
    }
    float bd = b_dt[d];
    float dsk = D_skip[d];
    int t0 = c * LCHUNK;
    for (int t = t0; t < t0 + LCHUNK; ++t) {
        float dtv = softplus_f(dt0[(long)t*D_INNER + d] + bd);
        float zv = zin[(long)t*D_INNER + d];
        float dz = dtv * zv;
        const float* xb = xdbl + (long)t*XDBL_W + DT_RANK;           // B
        const float* xc = xdbl + (long)t*XDBL_W + DT_RANK + D_STATE; // C
        float acc = dsk * zv;
        #pragma unroll
        for (int s = 0; s < 16; s++) {
            float ab = expf(dtv * negA[s]);
            hh[s] = fmaf(ab, hh[s], dz * xb[s]);
            acc = fmaf(hh[s], xc[s], acc);
        }
        y[(long)t*D_INNER + d] = acc;
    }
}

// ---------------- launch ----------------
extern "C" void kernel_launch(void* const* d_in, const int* in_sizes, int n_in,
                              void* d_out, int out_size, void* d_ws, size_t ws_size,
                              hipStream_t stream) {
    const float* x      = (const float*)d_in[0];
    const float* w_n1   = (const float*)d_in[1];
    const float* W_in   = (const float*)d_in[2];
    const float* W_gate = (const float*)d_in[3];
    const float* W_xp   = (const float*)d_in[4];
    const float* W_dt   = (const float*)d_in[5];
    const float* b_dt   = (const float*)d_in[6];
    const float* A_log  = (const float*)d_in[7];
    const float* D_skip = (const float*)d_in[8];
    const float* W_out  = (const float*)d_in[9];
    const float* w_n2   = (const float*)d_in[10];
    const float* W_up   = (const float*)d_in[11];
    const float* W_gff  = (const float*)d_in[12];
    const float* W_down = (const float*)d_in[13];

    float* ws   = (float*)d_ws;
    float* h    = ws;                 // 1572864  (reused as x2)
    float* z    = ws + 1572864;       // 3145728  (reused as y in-place)
    float* g    = ws + 4718592;       // 3145728  (reused as dt0, then hf)
    float* xdbl = ws + 7864320;       // 262144
    float* Aprod= ws + 8126464;       // 786432
    float* hend = ws + 8912896;       // 786432
    float* cin  = ws + 9699328;       // 786432
    float* up   = ws + 10485760;      // 4194304
    float* gf   = ws + 14680064;      // 4194304
    // total: 18874368 floats = 75.5 MB
    float* x2  = h;
    float* dt0 = g;
    float* hf  = g;

    dim3 blk(256);

    // 1. h = rmsnorm(x, w_norm1)
    rmsnorm_kernel<<<LSEQ, blk, 0, stream>>>(x, w_n1, h);
    // 2/3. z0 = h@W_in^T ; g0 = h@W_gate^T   [2048,1536]
    gemm_tn<0><<<dim3(D_INNER/64, LSEQ/64), blk, 0, stream>>>(h, D_MODEL, W_in, D_MODEL, nullptr, z, D_INNER, D_MODEL);
    gemm_tn<0><<<dim3(D_INNER/64, LSEQ/64), blk, 0, stream>>>(h, D_MODEL, W_gate, D_MODEL, nullptr, g, D_INNER, D_MODEL);
    // 4. z = z0 * sigmoid(g0)
    ew_gate<<<2048, blk, 0, stream>>>(z, g, z, LSEQ * D_INNER);
    // 5. xdbl = z @ W_xproj^T   [2048,128]
    gemm_tn<0><<<dim3(XDBL_W/64, LSEQ/64), blk, 0, stream>>>(z, D_INNER, W_xp, D_INNER, nullptr, xdbl, XDBL_W, D_INNER);
    // 6. dt0 = xdbl[:, :96] @ W_dt^T   [2048,1536]
    gemm_tn<0><<<dim3(D_INNER/64, LSEQ/64), blk, 0, stream>>>(xdbl, XDBL_W, W_dt, DT_RANK, nullptr, dt0, D_INNER, DT_RANK);
    // 7-9. selective scan -> y (in-place over z)
    scan_pass1<<<dim3(NCHUNK, D_INNER/256), blk, 0, stream>>>(dt0, b_dt, z, xdbl, A_log, Aprod, hend);
    scan_pass2<<<D_INNER/256, blk, 0, stream>>>(Aprod, hend, cin);
    scan_pass3<<<dim3(NCHUNK, D_INNER/256), blk, 0, stream>>>(dt0, b_dt, z, xdbl, A_log, cin, D_skip, z);
    // 10. x2 = x + y @ W_out^T   [2048,768]
    gemm_tn<1><<<dim3(D_MODEL/64, LSEQ/64), blk, 0, stream>>>(z, D_INNER, W_out, D_INNER, x, x2, D_MODEL, D_INNER);
    // 11. hf = rmsnorm(x2, w_ffn_norm)
    rmsnorm_kernel<<<LSEQ, blk, 0, stream>>>(x2, w_n2, hf);
    // 12/13. up = hf@W_up^T ; gf = hf@W_gate_ffn^T   [2048,2048]
    gemm_tn<0><<<dim3(H_FFN/64, LSEQ/64), blk, 0, stream>>>(hf, D_MODEL, W_up, D_MODEL, nullptr, up, H_FFN, D_MODEL);
    gemm_tn<0><<<dim3(H_FFN/64, LSEQ/64), blk, 0, stream>>>(hf, D_MODEL, W_gff, D_MODEL, nullptr, gf, H_FFN, D_MODEL);
    // 14. up = silu(gf) * up
    ew_silu_mul<<<2048, blk, 0, stream>>>(up, gf, LSEQ * H_FFN);
    // 15. out = x2 + up @ W_down^T   [2048,768]
    gemm_tn<1><<<dim3(D_MODEL/64, LSEQ/64), blk, 0, stream>>>(up, H_FFN, W_down, H_FFN, x2, (float*)d_out, D_MODEL, H_FFN);
}

// Round 2
// 499.564 us; speedup vs baseline: 2.2537x; 2.2537x over previous
//
#include <hip/hip_runtime.h>
#include <math.h>

#define D_MODEL 768
#define D_INNER 1536
#define D_STATE 16
#define DT_RANK 96
#define H_FFN 2048
#define LSEQ 2048
#define XDBL_W 128
#define NCHUNK 32
#define LCHUNK 64

typedef __attribute__((ext_vector_type(8))) short short8;
typedef __attribute__((ext_vector_type(4))) float f32x4;

__device__ __forceinline__ unsigned short f2bf(float f) {
    unsigned int u = __float_as_uint(f);
    unsigned int r = (u + 0x7fffu + ((u >> 16) & 1u)) >> 16;
    return (unsigned short)r;
}

__device__ __forceinline__ void load_lds16(const void* g, void* l) {
    __builtin_amdgcn_global_load_lds(
        (const __attribute__((address_space(1))) unsigned int*)g,
        (__attribute__((address_space(3))) unsigned int*)l,
        16, 0, 0);
}

// ---------------- bf16 MFMA GEMM: C[M,N] = A[M,K] @ B[N,K]^T (+Res) ----------
// BM=128, BN in {128,64}, BK=64, 256 threads (4 waves, 2x2 wave grid).
// LDS K-major tiles with XOR swizzle: linear DMA dest, inverse-swizzled global
// source, swizzled ds_read (rule 21).
template<int BN, int EPI, int BF16OUT>
__global__ __launch_bounds__(256) void gemm_mfma(
        const short* __restrict__ A, int lda,
        const short* __restrict__ B, int ldb,
        const float* __restrict__ Res, float* __restrict__ C,
        unsigned short* __restrict__ Cb, int N, int K) {
    constexpr int BM = 128;
    constexpr int WN = BN / 2;
    constexpr int FM = 4;
    constexpr int FN = WN / 16;
    __shared__ __attribute__((aligned(16))) short Al[BM * 64];
    __shared__ __attribute__((aligned(16))) short Bl[BN * 64];
    int tid = threadIdx.x;
    int w = tid >> 6, l = tid & 63;
    int wm = w >> 1, wn = w & 1;
    int bm0 = blockIdx.y * BM, bn0 = blockIdx.x * BN;
    int lr = l >> 3;            // row within 8-row chunk
    int lp = l & 7;             // linear 16B slot within row
    int swz = lp ^ lr;          // inverse-swizzled k-octet to fetch
    const short* Ag = A + (size_t)(bm0 + lr) * lda + swz * 8;
    const short* Bg = B + (size_t)(bn0 + lr) * ldb + swz * 8;

    f32x4 acc[FM][FN];
    #pragma unroll
    for (int mf = 0; mf < FM; ++mf)
        #pragma unroll
        for (int nf = 0; nf < FN; ++nf) acc[mf][nf] = (f32x4){0.f, 0.f, 0.f, 0.f};

    for (int k0 = 0; k0 < K; k0 += 64) {
        #pragma unroll
        for (int i = 0; i < BM / 32; ++i) {
            int c = w + 4 * i;
            load_lds16(Ag + (size_t)c * 8 * lda + k0, Al + c * 512);
        }
        #pragma unroll
        for (int i = 0; i < BN / 32; ++i) {
            int c = w + 4 * i;
            load_lds16(Bg + (size_t)c * 8 * ldb + k0, Bl + c * 512);
        }
        __syncthreads();   // compiler emits vmcnt(0) drain before barrier
        #pragma unroll
        for (int kh = 0; kh < 2; ++kh) {
            short8 af[FM], bfr[FN];
            #pragma unroll
            for (int mf = 0; mf < FM; ++mf) {
                int r = wm * 64 + mf * 16 + (l & 15);
                int sl = (kh * 4 + (l >> 4)) ^ (r & 7);
                af[mf] = *(const short8*)(Al + r * 64 + sl * 8);
            }
            #pragma unroll
            for (int nf = 0; nf < FN; ++nf) {
                int r = wn * WN + nf * 16 + (l & 15);
                int sl = (kh * 4 + (l >> 4)) ^ (r & 7);
                bfr[nf] = *(const short8*)(Bl + r * 64 + sl * 8);
            }
            #pragma unroll
            for (int mf = 0; mf < FM; ++mf)
                #pragma unroll
                for (int nf = 0; nf < FN; ++nf)
                    acc[mf][nf] = __builtin_amdgcn_mfma_f32_16x16x32_bf16(
                        af[mf], bfr[nf], acc[mf][nf], 0, 0, 0);
        }
        __syncthreads();
    }
    int cc = l & 15, rr4 = (l >> 4) * 4;
    #pragma unroll
    for (int mf = 0; mf < FM; ++mf)
        #pragma unroll
        for (int nf = 0; nf < FN; ++nf)
            #pragma unroll
            for (int j = 0; j < 4; ++j) {
                int m = bm0 + wm * 64 + mf * 16 + rr4 + j;
                int n = bn0 + wn * WN + nf * 16 + cc;
                size_t idx = (size_t)m * N + n;
                float v = acc[mf][nf][j];
                if (EPI == 1) v += Res[idx];
                C[idx] = v;
                if (BF16OUT) Cb[idx] = f2bf(v);
            }
}

// ---------------- weight fp32 -> bf16 arena (W_dt zero-padded 96->128) -------
#define WB_IN   0
#define WB_GATE 1179648
#define WB_XP   2359296
#define WB_DTP  2555904
#define WB_OUT  2752512
#define WB_UP   3932160
#define WB_GFF  5505024
#define WB_DOWN 7077888
#define WB_TOT  8650752

__global__ __launch_bounds__(256) void convert_weights(
        const float* __restrict__ Wi, const float* __restrict__ Wg,
        const float* __restrict__ Wx, const float* __restrict__ Wd,
        const float* __restrict__ Wo, const float* __restrict__ Wu,
        const float* __restrict__ Wf, const float* __restrict__ Ww,
        unsigned short* __restrict__ WB) {
    int e = (blockIdx.x * 256 + threadIdx.x) * 8;
    const float* s;
    int so;
    if (e < WB_GATE)      { s = Wi; so = e - WB_IN; }
    else if (e < WB_XP)   { s = Wg; so = e - WB_GATE; }
    else if (e < WB_DTP)  { s = Wx; so = e - WB_XP; }
    else if (e < WB_OUT)  {
        int i = e - WB_DTP, row = i >> 7, col = i & 127;
        if (col >= 96) {
            ushort4 z = {0, 0, 0, 0};
            *(ushort4*)(WB + e) = z;
            *(ushort4*)(WB + e + 4) = z;
            return;
        }
        s = Wd; so = row * 96 + col;
    }
    else if (e < WB_UP)   { s = Wo; so = e - WB_OUT; }
    else if (e < WB_GFF)  { s = Wu; so = e - WB_UP; }
    else if (e < WB_DOWN) { s = Wf; so = e - WB_GFF; }
    else                  { s = Ww; so = e - WB_DOWN; }
    float4 a = *(const float4*)(s + so);
    float4 b = *(const float4*)(s + so + 4);
    ushort4 o0 = {f2bf(a.x), f2bf(a.y), f2bf(a.z), f2bf(a.w)};
    ushort4 o1 = {f2bf(b.x), f2bf(b.y), f2bf(b.z), f2bf(b.w)};
    *(ushort4*)(WB + e) = o0;
    *(ushort4*)(WB + e + 4) = o1;
}

// ---------------- RMSNorm -> bf16 ----------------
__global__ __launch_bounds__(256) void rmsnorm_kernel(const float* __restrict__ x,
        const float* __restrict__ w, unsigned short* __restrict__ out) {
    int row = blockIdx.x;
    const float* xr = x + (long)row * D_MODEL;
    float v0 = xr[threadIdx.x];
    float v1 = xr[threadIdx.x + 256];
    float v2 = xr[threadIdx.x + 512];
    float ss = v0 * v0 + v1 * v1 + v2 * v2;
    #pragma unroll
    for (int off = 32; off > 0; off >>= 1) ss += __shfl_down(ss, off, 64);
    __shared__ float red[4];
    __shared__ float scale_sh;
    int wave = threadIdx.x >> 6, lane = threadIdx.x & 63;
    if (lane == 0) red[wave] = ss;
    __syncthreads();
    if (threadIdx.x == 0) {
        float tot = red[0] + red[1] + red[2] + red[3];
        scale_sh = rsqrtf(tot / (float)D_MODEL + 1e-6f);
    }
    __syncthreads();
    float sc = scale_sh;
    unsigned short* orow = out + (long)row * D_MODEL;
    orow[threadIdx.x]       = f2bf(v0 * sc * w[threadIdx.x]);
    orow[threadIdx.x + 256] = f2bf(v1 * sc * w[threadIdx.x + 256]);
    orow[threadIdx.x + 512] = f2bf(v2 * sc * w[threadIdx.x + 512]);
}

// ---------------- elementwise ----------------
__global__ void ew_gate(float* z0, const float* __restrict__ g0,
                        unsigned short* __restrict__ zb, int n4) {
    int i = blockIdx.x * blockDim.x + threadIdx.x;
    int stride = gridDim.x * blockDim.x;
    for (; i < n4; i += stride) {
        float4 z = *(float4*)(z0 + i * 4);
        float4 g = *(const float4*)(g0 + i * 4);
        z.x = z.x / (1.f + expf(-g.x));
        z.y = z.y / (1.f + expf(-g.y));
        z.z = z.z / (1.f + expf(-g.z));
        z.w = z.w / (1.f + expf(-g.w));
        *(float4*)(z0 + i * 4) = z;
        ushort4 o = {f2bf(z.x), f2bf(z.y), f2bf(z.z), f2bf(z.w)};
        *(ushort4*)(zb + i * 4) = o;
    }
}

__global__ void ew_silu_mul(const float* __restrict__ up, const float* __restrict__ gf,
                            unsigned short* __restrict__ ob, int n4) {
    int i = blockIdx.x * blockDim.x + threadIdx.x;
    int stride = gridDim.x * blockDim.x;
    for (; i < n4; i += stride) {
        float4 u = *(const float4*)(up + i * 4);
        float4 g = *(const float4*)(gf + i * 4);
        u.x = u.x * g.x / (1.f + expf(-g.x));
        u.y = u.y * g.y / (1.f + expf(-g.y));
        u.z = u.z * g.z / (1.f + expf(-g.z));
        u.w = u.w * g.w / (1.f + expf(-g.w));
        ushort4 o = {f2bf(u.x), f2bf(u.y), f2bf(u.z), f2bf(u.w)};
        *(ushort4*)(ob + i * 4) = o;
    }
}

// ---------------- selective scan (3-pass chunked), fp32 ----------------
__device__ __forceinline__ float softplus_f(float x) {
    return (x > 20.f) ? x : log1pf(expf(x));
}

__global__ __launch_bounds__(256) void scan_pass1(const float* __restrict__ dt0,
        const float* __restrict__ b_dt, const float* __restrict__ z,
        const float* __restrict__ xdbl, const float* __restrict__ A_log,
        float* __restrict__ Aprod, float* __restrict__ hend) {
    int c = blockIdx.x;
    int d = blockIdx.y * 256 + threadIdx.x;
    float negA[16], Ap[16], hh[16];
    #pragma unroll
    for (int s = 0; s < 16; s++) {
        negA[s] = -expf(A_log[d * 16 + s]);
        Ap[s] = 1.f; hh[s] = 0.f;
    }
    float bd = b_dt[d];
    int t0 = c * LCHUNK;
    for (int t = t0; t < t0 + LCHUNK; ++t) {
        float dtv = softplus_f(dt0[(long)t * D_INNER + d] + bd);
        float zv = z[(long)t * D_INNER + d];
        float dz = dtv * zv;
        const float* xb = xdbl + (long)t * XDBL_W + DT_RANK;
        #pragma unroll
        for (int s = 0; s < 16; s++) {
            float ab = expf(dtv * negA[s]);
            hh[s] = fmaf(ab, hh[s], dz * xb[s]);
            Ap[s] *= ab;
        }
    }
    long base = ((long)c * D_INNER + d) * 16;
    #pragma unroll
    for (int s = 0; s < 16; s++) { Aprod[base + s] = Ap[s]; hend[base + s] = hh[s]; }
}

__global__ __launch_bounds__(256) void scan_pass2(const float* __restrict__ Aprod,
        const float* __restrict__ hend, float* __restrict__ carryin) {
    int d = blockIdx.x * 256 + threadIdx.x;
    float carry[16];
    #pragma unroll
    for (int s = 0; s < 16; s++) carry[s] = 0.f;
    for (int c = 0; c < NCHUNK; c++) {
        long base = ((long)c * D_INNER + d) * 16;
        #pragma unroll
        for (int s = 0; s < 16; s++) {
            carryin[base + s] = carry[s];
            carry[s] = fmaf(Aprod[base + s], carry[s], hend[base + s]);
        }
    }
}

__global__ __launch_bounds__(256) void scan_pass3(const float* __restrict__ dt0,
        const float* __restrict__ b_dt, const float* __restrict__ zin,
        const float* __restrict__ xdbl, const float* __restrict__ A_log,
        const float* __restrict__ carryin, const float* __restrict__ D_skip,
        unsigned short* __restrict__ yb) {
    int c = blockIdx.x;
    int d = blockIdx.y * 256 + threadIdx.x;
    float negA[16], hh[16];
    long cb = ((long)c * D_INNER + d) * 16;
    #pragma unroll
    for (int s = 0; s < 16; s++) {
        negA[s] = -expf(A_log[d * 16 + s]);
        hh[s] = carryin[cb + s];
    }
    float bd = b_dt[d];
    float dsk = D_skip[d];
    int t0 = c * LCHUNK;
    for (int t = t0; t < t0 + LCHUNK; ++t) {
        float dtv = softplus_f(dt0[(long)t * D_INNER + d] + bd);
        float zv = zin[(long)t * D_INNER + d];
        float dz = dtv * zv;
        const float* xb = xdbl + (long)t * XDBL_W + DT_RANK;
        const float* xc = xdbl + (long)t * XDBL_W + DT_RANK + D_STATE;
        float acc = dsk * zv;
        #pragma unroll
        for (int s = 0; s < 16; s++) {
            float ab = expf(dtv * negA[s]);
            hh[s] = fmaf(ab, hh[s], dz * xb[s]);
            acc = fmaf(hh[s], xc[s], acc);
        }
        yb[(long)t * D_INNER + d] = f2bf(acc);
    }
}

// ---------------- launch ----------------
extern "C" void kernel_launch(void* const* d_in, const int* in_sizes, int n_in,
                              void* d_out, int out_size, void* d_ws, size_t ws_size,
                              hipStream_t stream) {
    const float* x      = (const float*)d_in[0];
    const float* w_n1   = (const float*)d_in[1];
    const float* W_in   = (const float*)d_in[2];
    const float* W_gate = (const float*)d_in[3];
    const float* W_xp   = (const float*)d_in[4];
    const float* W_dt   = (const float*)d_in[5];
    const float* b_dt   = (const float*)d_in[6];
    const float* A_log  = (const float*)d_in[7];
    const float* D_skip = (const float*)d_in[8];
    const float* W_out  = (const float*)d_in[9];
    const float* w_n2   = (const float*)d_in[10];
    const float* W_up   = (const float*)d_in[11];
    const float* W_gff  = (const float*)d_in[12];
    const float* W_down = (const float*)d_in[13];

    float* wsf = (float*)d_ws;
    // fp32 regions (element offsets)
    float* z0  = wsf + 0;         // 3145728  (z after gating; UP aliases later)
    float* g0  = wsf + 3145728;   // 3145728  (dt0 alias)
    float* xd  = wsf + 6291456;   // 262144
    float* apr = wsf + 6553600;   // 786432
    float* hen = wsf + 7340032;   // 786432
    float* cin = wsf + 8126464;   // 786432
    float* x2  = wsf + 8912896;   // 1572864  -> f32 total 10485760
    float* up  = wsf + 0;         // 4194304  (aliases z0+g0 head, both dead)
    float* gf  = wsf + 4194304;   // 4194304  (aliases g0 tail/xd/scan, dead)
    float* dt0 = g0;

    // bf16 arena (unsigned short), after fp32 region
    unsigned short* wb = (unsigned short*)(wsf + 10485760);
    unsigned short* WB     = wb + 0;          // weights, 8650752
    unsigned short* h_b    = wb + 8650752;    // 1572864 (hf_b alias)
    unsigned short* z_b    = wb + 10223616;   // 3145728 (y_b alias)
    unsigned short* xd_b   = wb + 13369344;   // 262144  -> bf16 total 13631488
    unsigned short* y_b    = z_b;
    unsigned short* hf_b   = h_b;
    unsigned short* upg_b  = wb + 8650752;    // 4194304 (aliases h_b+z_b, dead)

    dim3 blk(256);

    convert_weights<<<4224, blk, 0, stream>>>(W_in, W_gate, W_xp, W_dt, W_out,
                                              W_up, W_gff, W_down, WB);
    // 1. h = rmsnorm(x) -> bf16
    rmsnorm_kernel<<<LSEQ, blk, 0, stream>>>(x, w_n1, h_b);
    // 2/3. z0 = h@W_in^T ; g0 = h@W_gate^T   [2048,1536] K=768
    gemm_mfma<128, 0, 0><<<dim3(D_INNER / 128, LSEQ / 128), blk, 0, stream>>>(
        (const short*)h_b, D_MODEL, (const short*)(WB + WB_IN), D_MODEL,
        nullptr, z0, nullptr, D_INNER, D_MODEL);
    gemm_mfma<128, 0, 0><<<dim3(D_INNER / 128, LSEQ / 128), blk, 0, stream>>>(
        (const short*)h_b, D_MODEL, (const short*)(WB + WB_GATE), D_MODEL,
        nullptr, g0, nullptr, D_INNER, D_MODEL);
    // 4. z = z0 * sigmoid(g0) -> f32 (in-place) + bf16
    ew_gate<<<2048, blk, 0, stream>>>(z0, g0, z_b, LSEQ * D_INNER / 4);
    // 5. xdbl = z @ W_xproj^T   [2048,128] K=1536 -> f32 + bf16
    gemm_mfma<64, 0, 1><<<dim3(XDBL_W / 64, LSEQ / 128), blk, 0, stream>>>(
        (const short*)z_b, D_INNER, (const short*)(WB + WB_XP), D_INNER,
        nullptr, xd, xd_b, XDBL_W, D_INNER);
    // 6. dt0 = xdbl_pad @ W_dt_pad^T   [2048,1536] K=128
    gemm_mfma<128, 0, 0><<<dim3(D_INNER / 128, LSEQ / 128), blk, 0, stream>>>(
        (const short*)xd_b, XDBL_W, (const short*)(WB + WB_DTP), XDBL_W,
        nullptr, dt0, nullptr, D_INNER, XDBL_W);
    // 7-9. selective scan -> y bf16
    scan_pass1<<<dim3(NCHUNK, D_INNER / 256), blk, 0, stream>>>(dt0, b_dt, z0, xd, A_log, apr, hen);
    scan_pass2<<<D_INNER / 256, blk, 0, stream>>>(apr, hen, cin);
    scan_pass3<<<dim3(NCHUNK, D_INNER / 256), blk, 0, stream>>>(dt0, b_dt, z0, xd, A_log, cin, D_skip, y_b);
    // 10. x2 = x + y @ W_out^T   [2048,768] K=1536
    gemm_mfma<128, 1, 0><<<dim3(D_MODEL / 128, LSEQ / 128), blk, 0, stream>>>(
        (const short*)y_b, D_INNER, (const short*)(WB + WB_OUT), D_INNER,
        x, x2, nullptr, D_MODEL, D_INNER);
    // 11. hf = rmsnorm(x2) -> bf16
    rmsnorm_kernel<<<LSEQ, blk, 0, stream>>>(x2, w_n2, hf_b);
    // 12/13. up = hf@W_up^T ; gf = hf@W_gate_ffn^T   [2048,2048] K=768
    gemm_mfma<128, 0, 0><<<dim3(H_FFN / 128, LSEQ / 128), blk, 0, stream>>>(
        (const short*)hf_b, D_MODEL, (const short*)(WB + WB_UP), D_MODEL,
        nullptr, up, nullptr, H_FFN, D_MODEL);
    gemm_mfma<128, 0, 0><<<dim3(H_FFN / 128, LSEQ / 128), blk, 0, stream>>>(
        (const short*)hf_b, D_MODEL, (const short*)(WB + WB_GFF), D_MODEL,
        nullptr, gf, nullptr, H_FFN, D_MODEL);
    // 14. upg = silu(gf) * up -> bf16
    ew_silu_mul<<<2048, blk, 0, stream>>>(up, gf, upg_b, LSEQ * H_FFN / 4);
    // 15. out = x2 + upg @ W_down^T   [2048,768] K=2048
    gemm_mfma<128, 1, 0><<<dim3(D_MODEL / 128, LSEQ / 128), blk, 0, stream>>>(
        (const short*)upg_b, H_FFN, (const short*)(WB + WB_DOWN), H_FFN,
        x2, (float*)d_out, nullptr, D_MODEL, H_FFN);
}

// Round 4
// 348.165 us; speedup vs baseline: 3.2337x; 1.4348x over previous
//
#include <hip/hip_runtime.h>
#include <math.h>

#define D_MODEL 768
#define D_INNER 1536
#define D_STATE 16
#define DT_RANK 96
#define H_FFN 2048
#define LSEQ 2048
#define XDBL_W 128
#define NCHUNK 64
#define LCHUNK 32
#define LOG2E 1.44269504088896340736f
#define LN2 0.69314718055994530942f

typedef __attribute__((ext_vector_type(8))) short short8;
typedef __attribute__((ext_vector_type(4))) float f32x4;

__device__ __forceinline__ unsigned short f2bf(float f) {
    unsigned int u = __float_as_uint(f);
    unsigned int r = (u + 0x7fffu + ((u >> 16) & 1u)) >> 16;
    return (unsigned short)r;
}
__device__ __forceinline__ float bf2f(unsigned short b) {
    return __uint_as_float(((unsigned int)b) << 16);
}
__device__ __forceinline__ float fexp2(float x) { return __builtin_amdgcn_exp2f(x); }
__device__ __forceinline__ float flog2(float x) { return __builtin_amdgcn_logf(x); }
__device__ __forceinline__ float frcp(float x)  { return __builtin_amdgcn_rcpf(x); }
__device__ __forceinline__ float sigmoid_fast(float x) {
    return frcp(1.f + fexp2(-x * LOG2E));
}
__device__ __forceinline__ float softplus_fast(float x) {
    float sp = flog2(1.f + fexp2(x * LOG2E)) * LN2;
    return (x > 20.f) ? x : sp;
}

__device__ __forceinline__ void load_lds16(const void* g, void* l) {
    __builtin_amdgcn_global_load_lds(
        (const __attribute__((address_space(1))) unsigned int*)g,
        (__attribute__((address_space(3))) unsigned int*)l,
        16, 0, 0);
}

// ---------------- bf16 MFMA GEMM: C[M,N] = A[M,K] @ B[N,K]^T (+Res) ----------
template<int BN, int EPI, int BF16OUT>
__global__ __launch_bounds__(256) void gemm_mfma(
        const short* __restrict__ A, int lda,
        const short* __restrict__ B, int ldb,
        const float* __restrict__ Res, float* __restrict__ C,
        unsigned short* __restrict__ Cb, int N, int K) {
    constexpr int BM = 128;
    constexpr int WN = BN / 2;
    constexpr int FM = 4;
    constexpr int FN = WN / 16;
    __shared__ __attribute__((aligned(16))) short Al[BM * 64];
    __shared__ __attribute__((aligned(16))) short Bl[BN * 64];
    int tid = threadIdx.x;
    int w = tid >> 6, l = tid & 63;
    int wm = w >> 1, wn = w & 1;
    int bm0 = blockIdx.y * BM, bn0 = blockIdx.x * BN;
    int lr = l >> 3;
    int lp = l & 7;
    int swz = lp ^ lr;
    const short* Ag = A + (size_t)(bm0 + lr) * lda + swz * 8;
    const short* Bg = B + (size_t)(bn0 + lr) * ldb + swz * 8;

    f32x4 acc[FM][FN];
    #pragma unroll
    for (int mf = 0; mf < FM; ++mf)
        #pragma unroll
        for (int nf = 0; nf < FN; ++nf) acc[mf][nf] = (f32x4){0.f, 0.f, 0.f, 0.f};

    for (int k0 = 0; k0 < K; k0 += 64) {
        #pragma unroll
        for (int i = 0; i < BM / 32; ++i) {
            int c = w + 4 * i;
            load_lds16(Ag + (size_t)c * 8 * lda + k0, Al + c * 512);
        }
        #pragma unroll
        for (int i = 0; i < BN / 32; ++i) {
            int c = w + 4 * i;
            load_lds16(Bg + (size_t)c * 8 * ldb + k0, Bl + c * 512);
        }
        __syncthreads();
        #pragma unroll
        for (int kh = 0; kh < 2; ++kh) {
            short8 af[FM], bfr[FN];
            #pragma unroll
            for (int mf = 0; mf < FM; ++mf) {
                int r = wm * 64 + mf * 16 + (l & 15);
                int sl = (kh * 4 + (l >> 4)) ^ (r & 7);
                af[mf] = *(const short8*)(Al + r * 64 + sl * 8);
            }
            #pragma unroll
            for (int nf = 0; nf < FN; ++nf) {
                int r = wn * WN + nf * 16 + (l & 15);
                int sl = (kh * 4 + (l >> 4)) ^ (r & 7);
                bfr[nf] = *(const short8*)(Bl + r * 64 + sl * 8);
            }
            #pragma unroll
            for (int mf = 0; mf < FM; ++mf)
                #pragma unroll
                for (int nf = 0; nf < FN; ++nf)
                    acc[mf][nf] = __builtin_amdgcn_mfma_f32_16x16x32_bf16(
                        af[mf], bfr[nf], acc[mf][nf], 0, 0, 0);
        }
        __syncthreads();
    }
    int cc = l & 15, rr4 = (l >> 4) * 4;
    #pragma unroll
    for (int mf = 0; mf < FM; ++mf)
        #pragma unroll
        for (int nf = 0; nf < FN; ++nf)
            #pragma unroll
            for (int j = 0; j < 4; ++j) {
                int m = bm0 + wm * 64 + mf * 16 + rr4 + j;
                int n = bn0 + wn * WN + nf * 16 + cc;
                size_t idx = (size_t)m * N + n;
                float v = acc[mf][nf][j];
                if (EPI == 1) v += Res[idx];
                C[idx] = v;
                if (BF16OUT) Cb[idx] = f2bf(v);
            }
}

// ---------------- weight fp32 -> bf16 arena (W_dt zero-padded 96->128) -------
#define WB_IN   0
#define WB_GATE 1179648
#define WB_XP   2359296
#define WB_DTP  2555904
#define WB_OUT  2752512
#define WB_UP   3932160
#define WB_GFF  5505024
#define WB_DOWN 7077888
#define WB_TOT  8650752

__global__ __launch_bounds__(256) void convert_weights(
        const float* __restrict__ Wi, const float* __restrict__ Wg,
        const float* __restrict__ Wx, const float* __restrict__ Wd,
        const float* __restrict__ Wo, const float* __restrict__ Wu,
        const float* __restrict__ Wf, const float* __restrict__ Ww,
        unsigned short* __restrict__ WB) {
    int e = (blockIdx.x * 256 + threadIdx.x) * 8;
    const float* s;
    int so;
    if (e < WB_GATE)      { s = Wi; so = e - WB_IN; }
    else if (e < WB_XP)   { s = Wg; so = e - WB_GATE; }
    else if (e < WB_DTP)  { s = Wx; so = e - WB_XP; }
    else if (e < WB_OUT)  {
        int i = e - WB_DTP, row = i >> 7, col = i & 127;
        if (col >= 96) {
            ushort4 z = {0, 0, 0, 0};
            *(ushort4*)(WB + e) = z;
            *(ushort4*)(WB + e + 4) = z;
            return;
        }
        s = Wd; so = row * 96 + col;
    }
    else if (e < WB_UP)   { s = Wo; so = e - WB_OUT; }
    else if (e < WB_GFF)  { s = Wu; so = e - WB_UP; }
    else if (e < WB_DOWN) { s = Wf; so = e - WB_GFF; }
    else                  { s = Ww; so = e - WB_DOWN; }
    float4 a = *(const float4*)(s + so);
    float4 b = *(const float4*)(s + so + 4);
    ushort4 o0 = {f2bf(a.x), f2bf(a.y), f2bf(a.z), f2bf(a.w)};
    ushort4 o1 = {f2bf(b.x), f2bf(b.y), f2bf(b.z), f2bf(b.w)};
    *(ushort4*)(WB + e) = o0;
    *(ushort4*)(WB + e + 4) = o1;
}

// ---------------- RMSNorm -> bf16 ----------------
__global__ __launch_bounds__(256) void rmsnorm_kernel(const float* __restrict__ x,
        const float* __restrict__ w, unsigned short* __restrict__ out) {
    int row = blockIdx.x;
    const float* xr = x + (long)row * D_MODEL;
    float v0 = xr[threadIdx.x];
    float v1 = xr[threadIdx.x + 256];
    float v2 = xr[threadIdx.x + 512];
    float ss = v0 * v0 + v1 * v1 + v2 * v2;
    #pragma unroll
    for (int off = 32; off > 0; off >>= 1) ss += __shfl_down(ss, off, 64);
    __shared__ float red[4];
    __shared__ float scale_sh;
    int wave = threadIdx.x >> 6, lane = threadIdx.x & 63;
    if (lane == 0) red[wave] = ss;
    __syncthreads();
    if (threadIdx.x == 0) {
        float tot = red[0] + red[1] + red[2] + red[3];
        scale_sh = rsqrtf(tot / (float)D_MODEL + 1e-6f);
    }
    __syncthreads();
    float sc = scale_sh;
    unsigned short* orow = out + (long)row * D_MODEL;
    orow[threadIdx.x]       = f2bf(v0 * sc * w[threadIdx.x]);
    orow[threadIdx.x + 256] = f2bf(v1 * sc * w[threadIdx.x + 256]);
    orow[threadIdx.x + 512] = f2bf(v2 * sc * w[threadIdx.x + 512]);
}

// ---------------- elementwise ----------------
__global__ void ew_gate(const float* __restrict__ z0, const float* __restrict__ g0,
                        unsigned short* __restrict__ zb, int n4) {
    int i = blockIdx.x * blockDim.x + threadIdx.x;
    int stride = gridDim.x * blockDim.x;
    for (; i < n4; i += stride) {
        float4 z = *(const float4*)(z0 + i * 4);
        float4 g = *(const float4*)(g0 + i * 4);
        z.x *= sigmoid_fast(g.x);
        z.y *= sigmoid_fast(g.y);
        z.z *= sigmoid_fast(g.z);
        z.w *= sigmoid_fast(g.w);
        ushort4 o = {f2bf(z.x), f2bf(z.y), f2bf(z.z), f2bf(z.w)};
        *(ushort4*)(zb + i * 4) = o;
    }
}

__global__ void ew_silu_mul(const float* __restrict__ up, const float* __restrict__ gf,
                            unsigned short* __restrict__ ob, int n4) {
    int i = blockIdx.x * blockDim.x + threadIdx.x;
    int stride = gridDim.x * blockDim.x;
    for (; i < n4; i += stride) {
        float4 u = *(const float4*)(up + i * 4);
        float4 g = *(const float4*)(gf + i * 4);
        u.x *= g.x * sigmoid_fast(g.x);
        u.y *= g.y * sigmoid_fast(g.y);
        u.z *= g.z * sigmoid_fast(g.z);
        u.w *= g.w * sigmoid_fast(g.w);
        ushort4 o = {f2bf(u.x), f2bf(u.y), f2bf(u.z), f2bf(u.w)};
        *(ushort4*)(ob + i * 4) = o;
    }
}

// ---------------- selective scan (3-pass chunked), fp32 state ----------------
// summaries in [c][s][d] layout: idx = (c*16+s)*1536 + d  (coalesced over d)
__global__ __launch_bounds__(256) void scan_pass1(const float* __restrict__ dt0,
        const float* __restrict__ b_dt, const unsigned short* __restrict__ zb,
        const float* __restrict__ xdbl, const float* __restrict__ A_log,
        float* __restrict__ apr, float* __restrict__ hen) {
    int c = blockIdx.x;
    int d = blockIdx.y * 256 + threadIdx.x;
    float nA[16], Ap[16], hh[16];
    #pragma unroll
    for (int s = 0; s < 16; s++) {
        nA[s] = -fexp2(A_log[d * 16 + s] * LOG2E) * LOG2E;
        Ap[s] = 1.f; hh[s] = 0.f;
    }
    float bd = b_dt[d];
    int t0 = c * LCHUNK;
    for (int t = t0; t < t0 + LCHUNK; ++t) {
        float dtv = softplus_fast(dt0[(long)t * D_INNER + d] + bd);
        float zv = bf2f(zb[(long)t * D_INNER + d]);
        float dz = dtv * zv;
        const float4* xb4 = (const float4*)(xdbl + (long)t * XDBL_W + DT_RANK);
        float xb[16];
        *(float4*)(xb + 0)  = xb4[0];
        *(float4*)(xb + 4)  = xb4[1];
        *(float4*)(xb + 8)  = xb4[2];
        *(float4*)(xb + 12) = xb4[3];
        #pragma unroll
        for (int s = 0; s < 16; s++) {
            float ab = fexp2(dtv * nA[s]);
            hh[s] = fmaf(ab, hh[s], dz * xb[s]);
            Ap[s] *= ab;
        }
    }
    #pragma unroll
    for (int s = 0; s < 16; s++) {
        long i = (long)(c * 16 + s) * D_INNER + d;
        apr[i] = Ap[s];
        hen[i] = hh[s];
    }
}

// one thread per (s, d): register carry chain over chunks, coalesced loads
__global__ __launch_bounds__(256) void scan_pass2(const float* __restrict__ apr,
        const float* __restrict__ hen, float* __restrict__ cin) {
    int s = blockIdx.x / 6;
    int d = (blockIdx.x % 6) * 256 + threadIdx.x;
    float carry = 0.f;
    #pragma unroll 4
    for (int c = 0; c < NCHUNK; c++) {
        long i = (long)(c * 16 + s) * D_INNER + d;
        cin[i] = carry;
        carry = fmaf(apr[i], carry, hen[i]);
    }
}

__global__ __launch_bounds__(256) void scan_pass3(const float* __restrict__ dt0,
        const float* __restrict__ b_dt, const unsigned short* __restrict__ zb,
        const float* __restrict__ xdbl, const float* __restrict__ A_log,
        const float* __restrict__ cin, const float* __restrict__ D_skip,
        unsigned short* __restrict__ yb) {
    int c = blockIdx.x;
    int d = blockIdx.y * 256 + threadIdx.x;
    float nA[16], hh[16];
    #pragma unroll
    for (int s = 0; s < 16; s++) {
        nA[s] = -fexp2(A_log[d * 16 + s] * LOG2E) * LOG2E;
        hh[s] = cin[(long)(c * 16 + s) * D_INNER + d];
    }
    float bd = b_dt[d];
    float dsk = D_skip[d];
    int t0 = c * LCHUNK;
    for (int t = t0; t < t0 + LCHUNK; ++t) {
        float dtv = softplus_fast(dt0[(long)t * D_INNER + d] + bd);
        float zv = bf2f(zb[(long)t * D_INNER + d]);
        float dz = dtv * zv;
        const float4* xr4 = (const float4*)(xdbl + (long)t * XDBL_W + DT_RANK);
        float xb[16], xc[16];
        *(float4*)(xb + 0)  = xr4[0];
        *(float4*)(xb + 4)  = xr4[1];
        *(float4*)(xb + 8)  = xr4[2];
        *(float4*)(xb + 12) = xr4[3];
        *(float4*)(xc + 0)  = xr4[4];
        *(float4*)(xc + 4)  = xr4[5];
        *(float4*)(xc + 8)  = xr4[6];
        *(float4*)(xc + 12) = xr4[7];
        float acc = dsk * zv;
        #pragma unroll
        for (int s = 0; s < 16; s++) {
            float ab = fexp2(dtv * nA[s]);
            hh[s] = fmaf(ab, hh[s], dz * xb[s]);
            acc = fmaf(hh[s], xc[s], acc);
        }
        yb[(long)t * D_INNER + d] = f2bf(acc);
    }
}

// ---------------- launch ----------------
extern "C" void kernel_launch(void* const* d_in, const int* in_sizes, int n_in,
                              void* d_out, int out_size, void* d_ws, size_t ws_size,
                              hipStream_t stream) {
    const float* x      = (const float*)d_in[0];
    const float* w_n1   = (const float*)d_in[1];
    const float* W_in   = (const float*)d_in[2];
    const float* W_gate = (const float*)d_in[3];
    const float* W_xp   = (const float*)d_in[4];
    const float* W_dt   = (const float*)d_in[5];
    const float* b_dt   = (const float*)d_in[6];
    const float* A_log  = (const float*)d_in[7];
    const float* D_skip = (const float*)d_in[8];
    const float* W_out  = (const float*)d_in[9];
    const float* w_n2   = (const float*)d_in[10];
    const float* W_up   = (const float*)d_in[11];
    const float* W_gff  = (const float*)d_in[12];
    const float* W_down = (const float*)d_in[13];

    float* wsf = (float*)d_ws;
    // fp32 arena (element offsets), lifetime-overlaid:
    float* z0  = wsf + 0;         // 3145728   [gemm2 .. ew_gate]
    float* g0  = wsf + 3145728;   // 3145728   [gemm3 .. ew_gate], dt0 alias [gemm6 .. pass3]
    float* apr = wsf + 0;         // 1572864   [pass1 .. pass2]  (over dead z0)
    float* hen = wsf + 1572864;   // 1572864   [pass1 .. pass2]  (over dead z0)
    float* cin = wsf + 6291456;   // 1572864   [pass2 .. pass3]
    float* xd  = wsf + 7864320;   // 262144    [gemm5 .. pass3]
    float* x2  = wsf + 8388608;   // 1572864   [gemm10 .. end]
    float* up  = wsf + 0;         // 4194304   [gemm12 .. ew_silu] (over dead z0/apr/hen/dt0-head)
    float* gf  = wsf + 4194304;   // 4194304   [gemm13 .. ew_silu] (over dead dt0-tail/cin/xd)
    float* dt0 = g0;
    // f32 total: 9961472 floats

    unsigned short* wb = (unsigned short*)(wsf + 9961472);
    unsigned short* WB    = wb + 0;          // 8650752  weights, whole launch
    unsigned short* h_b   = wb + 8650752;    // 1572864  (hf_b alias)
    unsigned short* z_b   = wb + 10223616;   // 3145728  [ew_gate .. pass3]
    unsigned short* xd_b  = wb + 13369344;   // 262144   [gemm5 .. gemm6]
    unsigned short* y_b   = wb + 13631488;   // 3145728  [pass3 .. gemm10]
    unsigned short* hf_b  = h_b;
    unsigned short* upg_b = wb + 8650752;    // 4194304  [ew_silu .. gemm15] (over dead h_b/z_b head)
    // bf16 total: 16777216 shorts -> ws total ~73.4 MB

    dim3 blk(256);

    convert_weights<<<4224, blk, 0, stream>>>(W_in, W_gate, W_xp, W_dt, W_out,
                                              W_up, W_gff, W_down, WB);
    rmsnorm_kernel<<<LSEQ, blk, 0, stream>>>(x, w_n1, h_b);
    gemm_mfma<128, 0, 0><<<dim3(D_INNER / 128, LSEQ / 128), blk, 0, stream>>>(
        (const short*)h_b, D_MODEL, (const short*)(WB + WB_IN), D_MODEL,
        nullptr, z0, nullptr, D_INNER, D_MODEL);
    gemm_mfma<128, 0, 0><<<dim3(D_INNER / 128, LSEQ / 128), blk, 0, stream>>>(
        (const short*)h_b, D_MODEL, (const short*)(WB + WB_GATE), D_MODEL,
        nullptr, g0, nullptr, D_INNER, D_MODEL);
    ew_gate<<<2048, blk, 0, stream>>>(z0, g0, z_b, LSEQ * D_INNER / 4);
    gemm_mfma<64, 0, 1><<<dim3(XDBL_W / 64, LSEQ / 128), blk, 0, stream>>>(
        (const short*)z_b, D_INNER, (const short*)(WB + WB_XP), D_INNER,
        nullptr, xd, xd_b, XDBL_W, D_INNER);
    gemm_mfma<128, 0, 0><<<dim3(D_INNER / 128, LSEQ / 128), blk, 0, stream>>>(
        (const short*)xd_b, XDBL_W, (const short*)(WB + WB_DTP), XDBL_W,
        nullptr, dt0, nullptr, D_INNER, XDBL_W);
    scan_pass1<<<dim3(NCHUNK, D_INNER / 256), blk, 0, stream>>>(dt0, b_dt, z_b, xd, A_log, apr, hen);
    scan_pass2<<<16 * 6, blk, 0, stream>>>(apr, hen, cin);
    scan_pass3<<<dim3(NCHUNK, D_INNER / 256), blk, 0, stream>>>(dt0, b_dt, z_b, xd, A_log, cin, D_skip, y_b);
    gemm_mfma<128, 1, 0><<<dim3(D_MODEL / 128, LSEQ / 128), blk, 0, stream>>>(
        (const short*)y_b, D_INNER, (const short*)(WB + WB_OUT), D_INNER,
        x, x2, nullptr, D_MODEL, D_INNER);
    rmsnorm_kernel<<<LSEQ, blk, 0, stream>>>(x2, w_n2, hf_b);
    gemm_mfma<128, 0, 0><<<dim3(H_FFN / 128, LSEQ / 128), blk, 0, stream>>>(
        (const short*)hf_b, D_MODEL, (const short*)(WB + WB_UP), D_MODEL,
        nullptr, up, nullptr, H_FFN, D_MODEL);
    gemm_mfma<128, 0, 0><<<dim3(H_FFN / 128, LSEQ / 128), blk, 0, stream>>>(
        (const short*)hf_b, D_MODEL, (const short*)(WB + WB_GFF), D_MODEL,
        nullptr, gf, nullptr, H_FFN, D_MODEL);
    ew_silu_mul<<<2048, blk, 0, stream>>>(up, gf, upg_b, LSEQ * H_FFN / 4);
    gemm_mfma<128, 1, 0><<<dim3(D_MODEL / 128, LSEQ / 128), blk, 0, stream>>>(
        (const short*)upg_b, H_FFN, (const short*)(WB + WB_DOWN), H_FFN,
        x2, (float*)d_out, nullptr, D_MODEL, H_FFN);
}

// Round 5
// 256.330 us; speedup vs baseline: 4.3922x; 1.3583x over previous
//
#include <hip/hip_runtime.h>
#include <math.h>

#define D_MODEL 768
#define D_INNER 1536
#define D_STATE 16
#define DT_RANK 96
#define H_FFN 2048
#define LSEQ 2048
#define XDBL_W 128
#define NCHUNK 64
#define LCHUNK 32
#define LOG2E 1.44269504088896340736f
#define LN2 0.69314718055994530942f

typedef __attribute__((ext_vector_type(8))) short short8;
typedef __attribute__((ext_vector_type(4))) float f32x4;

__device__ __forceinline__ unsigned short f2bf(float f) {
    unsigned int u = __float_as_uint(f);
    unsigned int r = (u + 0x7fffu + ((u >> 16) & 1u)) >> 16;
    return (unsigned short)r;
}
__device__ __forceinline__ float bf2f(unsigned short b) {
    return __uint_as_float(((unsigned int)b) << 16);
}
__device__ __forceinline__ float fexp2(float x) { return __builtin_amdgcn_exp2f(x); }
__device__ __forceinline__ float flog2(float x) { return __builtin_amdgcn_logf(x); }
__device__ __forceinline__ float frcp(float x)  { return __builtin_amdgcn_rcpf(x); }
__device__ __forceinline__ float sigmoid_fast(float x) {
    return frcp(1.f + fexp2(-x * LOG2E));
}
__device__ __forceinline__ float softplus_fast(float x) {
    float sp = flog2(1.f + fexp2(x * LOG2E)) * LN2;
    return (x > 20.f) ? x : sp;
}

__device__ __forceinline__ void load_lds16(const void* g, void* l) {
    __builtin_amdgcn_global_load_lds(
        (const __attribute__((address_space(1))) unsigned int*)g,
        (__attribute__((address_space(3))) unsigned int*)l,
        16, 0, 0);
}

// ---------------- bf16 MFMA GEMM: C[M,N] = A[M,K] @ B[N,K]^T ----------------
// 4 waves in 2x2 grid; wave tile (BM/2)x(BN/2). K-step 64, XOR-swizzled LDS.
// EPI: 0 = f32 C; 1 = f32 C + Res add; 2 = gated a*sigmoid(b) -> bf16 Cb
// (B rows interleaved in 16-row groups, output N/2 wide); 3 = a*b*sigmoid(b).
// BF16OUT: additionally write bf16 copy of f32 C.
template<int BM, int BN, int EPI, int BF16OUT>
__global__ __launch_bounds__(256) void gemm_mfma(
        const short* __restrict__ A, int lda,
        const short* __restrict__ B, int ldb,
        const float* __restrict__ Res, float* __restrict__ C,
        unsigned short* __restrict__ Cb, int N, int K) {
    constexpr int WM = BM / 2;
    constexpr int WN = BN / 2;
    constexpr int FM = WM / 16;
    constexpr int FN = WN / 16;
    __shared__ __attribute__((aligned(16))) short Al[BM * 64];
    __shared__ __attribute__((aligned(16))) short Bl[BN * 64];
    int tid = threadIdx.x;
    int w = tid >> 6, l = tid & 63;
    int wm = w >> 1, wn = w & 1;
    int bm0 = blockIdx.y * BM, bn0 = blockIdx.x * BN;
    int lr = l >> 3;
    int lp = l & 7;
    int swz = lp ^ lr;
    const short* Ag = A + (size_t)(bm0 + lr) * lda + swz * 8;
    const short* Bg = B + (size_t)(bn0 + lr) * ldb + swz * 8;

    f32x4 acc[FM][FN];
    #pragma unroll
    for (int mf = 0; mf < FM; ++mf)
        #pragma unroll
        for (int nf = 0; nf < FN; ++nf) acc[mf][nf] = (f32x4){0.f, 0.f, 0.f, 0.f};

    for (int k0 = 0; k0 < K; k0 += 64) {
        #pragma unroll
        for (int i = 0; i < BM / 32; ++i) {
            int c = w + 4 * i;
            load_lds16(Ag + (size_t)c * 8 * lda + k0, Al + c * 512);
        }
        #pragma unroll
        for (int i = 0; i < BN / 32; ++i) {
            int c = w + 4 * i;
            load_lds16(Bg + (size_t)c * 8 * ldb + k0, Bl + c * 512);
        }
        __syncthreads();
        #pragma unroll
        for (int kh = 0; kh < 2; ++kh) {
            short8 af[FM], bfr[FN];
            #pragma unroll
            for (int mf = 0; mf < FM; ++mf) {
                int r = wm * WM + mf * 16 + (l & 15);
                int sl = (kh * 4 + (l >> 4)) ^ (r & 7);
                af[mf] = *(const short8*)(Al + r * 64 + sl * 8);
            }
            #pragma unroll
            for (int nf = 0; nf < FN; ++nf) {
                int r = wn * WN + nf * 16 + (l & 15);
                int sl = (kh * 4 + (l >> 4)) ^ (r & 7);
                bfr[nf] = *(const short8*)(Bl + r * 64 + sl * 8);
            }
            #pragma unroll
            for (int mf = 0; mf < FM; ++mf)
                #pragma unroll
                for (int nf = 0; nf < FN; ++nf)
                    acc[mf][nf] = __builtin_amdgcn_mfma_f32_16x16x32_bf16(
                        af[mf], bfr[nf], acc[mf][nf], 0, 0, 0);
        }
        __syncthreads();
    }
    int cc = l & 15, rr4 = (l >> 4) * 4;
    if (EPI >= 2) {
        // fused pair epilogue: even frag = a (W_in/W_up), odd frag = b (gate)
        #pragma unroll
        for (int mf = 0; mf < FM; ++mf)
            #pragma unroll
            for (int p = 0; p < FN / 2; ++p)
                #pragma unroll
                for (int j = 0; j < 4; ++j) {
                    int m = bm0 + wm * WM + mf * 16 + rr4 + j;
                    int n = (bn0 + wn * WN) / 2 + p * 16 + cc;
                    float va = acc[mf][2 * p][j];
                    float vb = acc[mf][2 * p + 1][j];
                    float v = (EPI == 2) ? va * sigmoid_fast(vb)
                                         : va * vb * sigmoid_fast(vb);
                    Cb[(size_t)m * (N / 2) + n] = f2bf(v);
                }
    } else {
        #pragma unroll
        for (int mf = 0; mf < FM; ++mf)
            #pragma unroll
            for (int nf = 0; nf < FN; ++nf)
                #pragma unroll
                for (int j = 0; j < 4; ++j) {
                    int m = bm0 + wm * WM + mf * 16 + rr4 + j;
                    int n = bn0 + wn * WN + nf * 16 + cc;
                    size_t idx = (size_t)m * N + n;
                    float v = acc[mf][nf][j];
                    if (EPI == 1) v += Res[idx];
                    C[idx] = v;
                    if (BF16OUT) Cb[idx] = f2bf(v);
                }
    }
}

// ---------------- weight fp32 -> bf16 arena ----------------
// WB_INGATE: [W_in;W_gate] interleaved 16-row groups (3072 x 768)
// WB_UPGFF:  [W_up;W_gate_ffn] interleaved 16-row groups (4096 x 768)
// WB_DTP: W_dt zero-padded 96->128 cols.
#define WB_INGATE 0
#define WB_XP     2359296
#define WB_DTP    2555904
#define WB_OUT    2752512
#define WB_UPGFF  3932160
#define WB_DOWN   7077888
#define WB_TOT    8650752

__global__ __launch_bounds__(256) void convert_weights(
        const float* __restrict__ Wi, const float* __restrict__ Wg,
        const float* __restrict__ Wx, const float* __restrict__ Wd,
        const float* __restrict__ Wo, const float* __restrict__ Wu,
        const float* __restrict__ Wf, const float* __restrict__ Ww,
        unsigned short* __restrict__ WB) {
    int e = (blockIdx.x * 256 + threadIdx.x) * 8;
    const float* s;
    long so;
    if (e < WB_XP) {
        int i = e - WB_INGATE;
        int row = i / D_MODEL, col = i % D_MODEL;
        int p = row >> 5, wd = row & 31;
        if (wd < 16) { s = Wi; so = (long)(p * 16 + wd) * D_MODEL + col; }
        else         { s = Wg; so = (long)(p * 16 + wd - 16) * D_MODEL + col; }
    }
    else if (e < WB_DTP)  { s = Wx; so = e - WB_XP; }
    else if (e < WB_OUT)  {
        int i = e - WB_DTP, row = i >> 7, col = i & 127;
        if (col >= 96) {
            ushort4 z = {0, 0, 0, 0};
            *(ushort4*)(WB + e) = z;
            *(ushort4*)(WB + e + 4) = z;
            return;
        }
        s = Wd; so = row * 96 + col;
    }
    else if (e < WB_UPGFF) { s = Wo; so = e - WB_OUT; }
    else if (e < WB_DOWN) {
        int i = e - WB_UPGFF;
        int row = i / D_MODEL, col = i % D_MODEL;
        int p = row >> 5, wd = row & 31;
        if (wd < 16) { s = Wu; so = (long)(p * 16 + wd) * D_MODEL + col; }
        else         { s = Wf; so = (long)(p * 16 + wd - 16) * D_MODEL + col; }
    }
    else                  { s = Ww; so = e - WB_DOWN; }
    float4 a = *(const float4*)(s + so);
    float4 b = *(const float4*)(s + so + 4);
    ushort4 o0 = {f2bf(a.x), f2bf(a.y), f2bf(a.z), f2bf(a.w)};
    ushort4 o1 = {f2bf(b.x), f2bf(b.y), f2bf(b.z), f2bf(b.w)};
    *(ushort4*)(WB + e) = o0;
    *(ushort4*)(WB + e + 4) = o1;
}

// ---------------- RMSNorm -> bf16 ----------------
__global__ __launch_bounds__(256) void rmsnorm_kernel(const float* __restrict__ x,
        const float* __restrict__ w, unsigned short* __restrict__ out) {
    int row = blockIdx.x;
    const float* xr = x + (long)row * D_MODEL;
    float v0 = xr[threadIdx.x];
    float v1 = xr[threadIdx.x + 256];
    float v2 = xr[threadIdx.x + 512];
    float ss = v0 * v0 + v1 * v1 + v2 * v2;
    #pragma unroll
    for (int off = 32; off > 0; off >>= 1) ss += __shfl_down(ss, off, 64);
    __shared__ float red[4];
    __shared__ float scale_sh;
    int wave = threadIdx.x >> 6, lane = threadIdx.x & 63;
    if (lane == 0) red[wave] = ss;
    __syncthreads();
    if (threadIdx.x == 0) {
        float tot = red[0] + red[1] + red[2] + red[3];
        scale_sh = rsqrtf(tot / (float)D_MODEL + 1e-6f);
    }
    __syncthreads();
    float sc = scale_sh;
    unsigned short* orow = out + (long)row * D_MODEL;
    orow[threadIdx.x]       = f2bf(v0 * sc * w[threadIdx.x]);
    orow[threadIdx.x + 256] = f2bf(v1 * sc * w[threadIdx.x + 256]);
    orow[threadIdx.x + 512] = f2bf(v2 * sc * w[threadIdx.x + 512]);
}

// ---------------- selective scan (3-pass chunked), fp32 state ----------------
__global__ __launch_bounds__(256) void scan_pass1(const float* __restrict__ dt0,
        const float* __restrict__ b_dt, const unsigned short* __restrict__ zb,
        const float* __restrict__ xdbl, const float* __restrict__ A_log,
        float* __restrict__ apr, float* __restrict__ hen) {
    int c = blockIdx.x;
    int d = blockIdx.y * 256 + threadIdx.x;
    float nA[16], Ap[16], hh[16];
    #pragma unroll
    for (int s = 0; s < 16; s++) {
        nA[s] = -fexp2(A_log[d * 16 + s] * LOG2E) * LOG2E;
        Ap[s] = 1.f; hh[s] = 0.f;
    }
    float bd = b_dt[d];
    int t0 = c * LCHUNK;
    for (int t = t0; t < t0 + LCHUNK; ++t) {
        float dtv = softplus_fast(dt0[(long)t * D_INNER + d] + bd);
        float zv = bf2f(zb[(long)t * D_INNER + d]);
        float dz = dtv * zv;
        const float4* xb4 = (const float4*)(xdbl + (long)t * XDBL_W + DT_RANK);
        float xb[16];
        *(float4*)(xb + 0)  = xb4[0];
        *(float4*)(xb + 4)  = xb4[1];
        *(float4*)(xb + 8)  = xb4[2];
        *(float4*)(xb + 12) = xb4[3];
        #pragma unroll
        for (int s = 0; s < 16; s++) {
            float ab = fexp2(dtv * nA[s]);
            hh[s] = fmaf(ab, hh[s], dz * xb[s]);
            Ap[s] *= ab;
        }
    }
    #pragma unroll
    for (int s = 0; s < 16; s++) {
        long i = (long)(c * 16 + s) * D_INNER + d;
        apr[i] = Ap[s];
        hen[i] = hh[s];
    }
}

__global__ __launch_bounds__(256) void scan_pass2(const float* __restrict__ apr,
        const float* __restrict__ hen, float* __restrict__ cin) {
    int s = blockIdx.x / 6;
    int d = (blockIdx.x % 6) * 256 + threadIdx.x;
    float carry = 0.f;
    #pragma unroll 4
    for (int c = 0; c < NCHUNK; c++) {
        long i = (long)(c * 16 + s) * D_INNER + d;
        cin[i] = carry;
        carry = fmaf(apr[i], carry, hen[i]);
    }
}

__global__ __launch_bounds__(256) void scan_pass3(const float* __restrict__ dt0,
        const float* __restrict__ b_dt, const unsigned short* __restrict__ zb,
        const float* __restrict__ xdbl, const float* __restrict__ A_log,
        const float* __restrict__ cin, const float* __restrict__ D_skip,
        unsigned short* __restrict__ yb) {
    int c = blockIdx.x;
    int d = blockIdx.y * 256 + threadIdx.x;
    float nA[16], hh[16];
    #pragma unroll
    for (int s = 0; s < 16; s++) {
        nA[s] = -fexp2(A_log[d * 16 + s] * LOG2E) * LOG2E;
        hh[s] = cin[(long)(c * 16 + s) * D_INNER + d];
    }
    float bd = b_dt[d];
    float dsk = D_skip[d];
    int t0 = c * LCHUNK;
    for (int t = t0; t < t0 + LCHUNK; ++t) {
        float dtv = softplus_fast(dt0[(long)t * D_INNER + d] + bd);
        float zv = bf2f(zb[(long)t * D_INNER + d]);
        float dz = dtv * zv;
        const float4* xr4 = (const float4*)(xdbl + (long)t * XDBL_W + DT_RANK);
        float xb[16], xc[16];
        *(float4*)(xb + 0)  = xr4[0];
        *(float4*)(xb + 4)  = xr4[1];
        *(float4*)(xb + 8)  = xr4[2];
        *(float4*)(xb + 12) = xr4[3];
        *(float4*)(xc + 0)  = xr4[4];
        *(float4*)(xc + 4)  = xr4[5];
        *(float4*)(xc + 8)  = xr4[6];
        *(float4*)(xc + 12) = xr4[7];
        float acc = dsk * zv;
        #pragma unroll
        for (int s = 0; s < 16; s++) {
            float ab = fexp2(dtv * nA[s]);
            hh[s] = fmaf(ab, hh[s], dz * xb[s]);
            acc = fmaf(hh[s], xc[s], acc);
        }
        yb[(long)t * D_INNER + d] = f2bf(acc);
    }
}

// ---------------- launch ----------------
extern "C" void kernel_launch(void* const* d_in, const int* in_sizes, int n_in,
                              void* d_out, int out_size, void* d_ws, size_t ws_size,
                              hipStream_t stream) {
    const float* x      = (const float*)d_in[0];
    const float* w_n1   = (const float*)d_in[1];
    const float* W_in   = (const float*)d_in[2];
    const float* W_gate = (const float*)d_in[3];
    const float* W_xp   = (const float*)d_in[4];
    const float* W_dt   = (const float*)d_in[5];
    const float* b_dt   = (const float*)d_in[6];
    const float* A_log  = (const float*)d_in[7];
    const float* D_skip = (const float*)d_in[8];
    const float* W_out  = (const float*)d_in[9];
    const float* w_n2   = (const float*)d_in[10];
    const float* W_up   = (const float*)d_in[11];
    const float* W_gff  = (const float*)d_in[12];
    const float* W_down = (const float*)d_in[13];

    float* wsf = (float*)d_ws;
    // f32 arena (element offsets):
    float* dt0 = wsf + 0;         // 3145728  [dt-gemm .. pass3]
    float* xd  = wsf + 3145728;   // 262144   [xproj .. pass3]
    float* apr = wsf + 3407872;   // 1572864  [pass1 .. pass2]
    float* hen = wsf + 4980736;   // 1572864  [pass1 .. pass2]
    float* cin = wsf + 6553600;   // 1572864  [pass2 .. pass3]
    float* x2  = wsf + 8126464;   // 1572864  [outproj .. end]
    // f32 total 9699328

    unsigned short* wb = (unsigned short*)(wsf + 9699328);
    unsigned short* WB    = wb + 0;          // 8650752  weights
    unsigned short* h_b   = wb + 8650752;    // 1572864  (hf_b alias)
    unsigned short* z_b   = wb + 10223616;   // 3145728  [ingate .. pass3]
    unsigned short* xd_b  = wb + 13369344;   // 262144   [xproj .. dt-gemm]
    unsigned short* y_b   = wb + 13631488;   // 3145728  [pass3 .. outproj]
    unsigned short* hf_b  = h_b;
    unsigned short* upg_b = wb + 10223616;   // 4194304  [ffn .. down] (over dead z_b/xd_b/y_b)
    // bf16 total 16777216 -> ws ~72.3 MB

    dim3 blk(256);

    convert_weights<<<4224, blk, 0, stream>>>(W_in, W_gate, W_xp, W_dt, W_out,
                                              W_up, W_gff, W_down, WB);
    // 1. h = rmsnorm(x)
    rmsnorm_kernel<<<LSEQ, blk, 0, stream>>>(x, w_n1, h_b);
    // 2. fused z = (h@W_in^T) * sigmoid(h@W_gate^T) -> z_b   [2048,1536]
    gemm_mfma<64, 128, 2, 0><<<dim3(24, 32), blk, 0, stream>>>(
        (const short*)h_b, D_MODEL, (const short*)(WB + WB_INGATE), D_MODEL,
        nullptr, nullptr, z_b, 2 * D_INNER, D_MODEL);
    // 3. xdbl = z @ W_xproj^T   [2048,128]
    gemm_mfma<64, 64, 0, 1><<<dim3(2, 32), blk, 0, stream>>>(
        (const short*)z_b, D_INNER, (const short*)(WB + WB_XP), D_INNER,
        nullptr, xd, xd_b, XDBL_W, D_INNER);
    // 4. dt0 = xdbl_pad @ W_dt_pad^T   [2048,1536]
    gemm_mfma<64, 128, 0, 0><<<dim3(12, 32), blk, 0, stream>>>(
        (const short*)xd_b, XDBL_W, (const short*)(WB + WB_DTP), XDBL_W,
        nullptr, dt0, nullptr, D_INNER, XDBL_W);
    // 5-7. selective scan -> y_b
    scan_pass1<<<dim3(NCHUNK, D_INNER / 256), blk, 0, stream>>>(dt0, b_dt, z_b, xd, A_log, apr, hen);
    scan_pass2<<<16 * 6, blk, 0, stream>>>(apr, hen, cin);
    scan_pass3<<<dim3(NCHUNK, D_INNER / 256), blk, 0, stream>>>(dt0, b_dt, z_b, xd, A_log, cin, D_skip, y_b);
    // 8. x2 = x + y @ W_out^T   [2048,768]
    gemm_mfma<64, 64, 1, 0><<<dim3(12, 32), blk, 0, stream>>>(
        (const short*)y_b, D_INNER, (const short*)(WB + WB_OUT), D_INNER,
        x, x2, nullptr, D_MODEL, D_INNER);
    // 9. hf = rmsnorm(x2)
    rmsnorm_kernel<<<LSEQ, blk, 0, stream>>>(x2, w_n2, hf_b);
    // 10. fused upg = (hf@W_up^T) * silu(hf@W_gate_ffn^T) -> upg_b  [2048,2048]
    gemm_mfma<64, 128, 3, 0><<<dim3(32, 32), blk, 0, stream>>>(
        (const short*)hf_b, D_MODEL, (const short*)(WB + WB_UPGFF), D_MODEL,
        nullptr, nullptr, upg_b, 2 * H_FFN, D_MODEL);
    // 11. out = x2 + upg @ W_down^T   [2048,768]
    gemm_mfma<64, 64, 1, 0><<<dim3(12, 32), blk, 0, stream>>>(
        (const short*)upg_b, H_FFN, (const short*)(WB + WB_DOWN), H_FFN,
        x2, (float*)d_out, nullptr, D_MODEL, H_FFN);
}